// Round 5
// baseline (269.558 us; speedup 1.0000x reference)
//
#include <hip/hip_runtime.h>
#include <math.h>
#include <string.h>

#define K_SIZE 5
#define PAD 2
#define DEPTH_MAX 192.0f
#define S_NUM 15
#define G_NUM (K_SIZE * K_SIZE)   // 25

// Fixed problem shape (from reference setup_inputs):
#define B_DIM 2
#define C_DIM 32
#define H_DIM 256
#define W_DIM 512
#define HW (H_DIM * W_DIM)
// max |tap offset| = 2*W_DIM + 2 = 1026; safe margin rounded up
#define EDGE 1032

typedef float float4u __attribute__((ext_vector_type(4)));

__global__ __launch_bounds__(256, 4) void adaptive_sample_kernel(
    const float* __restrict__ depth,      // [B,1,H,W]
    const float* __restrict__ features,   // [B,C,H,W]
    const float* __restrict__ guide,      // [B,H,W,25]
    const int*   __restrict__ sample_idx, // [15]
    float*       __restrict__ out)        // [B,C,H,W] ++ [B,C,H,W] copy
{
    // Phase 1: wave-private guide staging (4 waves x 64 px x 25 = 25.6 KB).
    // Phase 2: same buffer recycled as weights[s][256] (15.4 KB).
    __shared__ float smem[4 * 64 * G_NUM];

    const int tid  = threadIdx.x;
    const int lane = tid & 63;
    const int wid  = tid >> 6;
    const int p0   = blockIdx.x * 256;       // block's first pixel
    const int p    = p0 + tid;               // phase-1 pixel of this thread
    const int x = p % W_DIM;
    const int y = (p / W_DIM) % H_DIM;
    const int b = p / HW;

    // ---- sample indices (wave-uniform -> scalar loads) ----
    int sidx[S_NUM];
#pragma unroll
    for (int s = 0; s < S_NUM; ++s) sidx[s] = sample_idx[s];

    // ================= PHASE 1: per-pixel softmax weights =================
    // coalesced guide staging into wave-private LDS
    {
        const int pw = p0 + (wid << 6);                 // wave's first pixel
        const float* gsrc = guide + (size_t)pw * G_NUM; // 1600 contiguous floats
        float* gw = &smem[wid * 64 * G_NUM];
#pragma unroll
        for (int k = 0; k < G_NUM; ++k)
            gw[lane + 64 * k] = gsrc[lane + 64 * k];    // fully coalesced
    }
    const float* grow = &smem[wid * 64 * G_NUM + lane * G_NUM]; // stride 25: no conflicts

    // gaussian positional weights, normalized
    float posw[S_NUM];
    float psum = 0.f;
#pragma unroll
    for (int s = 0; s < S_NUM; ++s) {
        const float px = (float)(sidx[s] % K_SIZE);
        const float py = (float)(sidx[s] / K_SIZE);
        const float ddx = px - (float)(K_SIZE / 2);
        const float ddy = py - (float)(K_SIZE / 2);
        posw[s] = expf(-0.5f * sqrtf(ddx * ddx + ddy * ddy));
        psum += posw[s];
    }
    const float inv_psum = 1.f / psum;

    // raw weights: valid(depth@tap) * pos_w * guide(center, idx)
    float raw[S_NUM];
    float inb_f[S_NUM];
    const int dbase = b * HW;
#pragma unroll
    for (int s = 0; s < S_NUM; ++s) {
        const int dy = sidx[s] / K_SIZE - PAD;
        const int dx = sidx[s] % K_SIZE - PAD;
        const int yy = y + dy;
        const int xx = x + dx;
        const bool inb = (yy >= 0) & (yy < H_DIM) & (xx >= 0) & (xx < W_DIM);
        float v = 0.f;
        if (inb) {
            const float d = depth[dbase + yy * W_DIM + xx];  // coalesced
            v = (d > 0.f && d < DEPTH_MAX) ? 1.f : 0.f;
        }
        raw[s]   = v * (posw[s] * inv_psum) * grow[sidx[s]];
        inb_f[s] = inb ? 1.f : 0.f;
    }

    // softmax over the 15 samples (matches jax.nn.softmax exactly)
    float mx = raw[0];
#pragma unroll
    for (int s = 1; s < S_NUM; ++s) mx = fmaxf(mx, raw[s]);
    float esum = 0.f;
    float wgt[S_NUM];
#pragma unroll
    for (int s = 0; s < S_NUM; ++s) {
        wgt[s] = expf(raw[s] - mx);
        esum += wgt[s];
    }
    const float inv_esum = 1.f / esum;

    // all waves done reading guide before weights overwrite the buffer
    __syncthreads();
#pragma unroll
    for (int s = 0; s < S_NUM; ++s)
        smem[s * 256 + tid] = wgt[s] * inv_esum * inb_f[s];  // OOB taps -> 0
    __syncthreads();

    // ============ PHASE 2: 4 pixels x 8 channels per thread ============
    const int g   = tid & 63;            // pixel-group within block
    const int c0  = (tid >> 6) * 8;      // first channel of this thread
    const int pg  = p0 + 4 * g;          // first of 4 consecutive pixels
    const int bb  = pg / HW;
    const int yx  = pg % HW;             // y*W + x0 (group never crosses a row)

    // per-sample weights for the 4 pixels (LDS, 16B-aligned)
    float4u wv[S_NUM];
#pragma unroll
    for (int s = 0; s < S_NUM; ++s)
        wv[s] = *(const float4u*)&smem[s * 256 + 4 * g];

    // plane-relative tap offsets (wave-uniform)
    int offr[S_NUM];
#pragma unroll
    for (int s = 0; s < S_NUM; ++s)
        offr[s] = (sidx[s] / K_SIZE - PAD) * W_DIM + (sidx[s] % K_SIZE - PAD);

    // Safe iff every tap's 4-wide load stays inside the plane. Taps that wrap
    // a row read wrong-row values but carry weight 0 (inb mask) -> harmless.
    const bool safe = (yx >= EDGE) && (yx <= HW - EDGE);

    const size_t feat = (size_t)B_DIM * C_DIM * HW;
    const float* fplane = features + ((size_t)bb * C_DIM + c0) * HW;
    float* o0 = out + ((size_t)bb * C_DIM + c0) * HW + yx;        // weighted sum
    float* o1 = o0 + feat;                                        // passthrough

    if (safe) {
#pragma unroll 2
        for (int c = 0; c < 8; ++c) {
            const float4u cv = *(const float4u*)(fplane + yx);    // aligned
            float4u acc = {0.f, 0.f, 0.f, 0.f};
#pragma unroll
            for (int s = 0; s < S_NUM; ++s) {
                float4u v;
                __builtin_memcpy(&v, fplane + yx + offr[s], 16);  // dword-aligned x4
                acc += wv[s] * v;
            }
            *(float4u*)o0 = acc;
            *(float4u*)o1 = cv;
            fplane += HW;
            o0 += HW;
            o1 += HW;
        }
    } else {
        // Boundary groups (first/last 2 rows of each plane): per-pixel scalar
        // taps with per-pixel clamping (clamped value only read when wgt==0).
        for (int c = 0; c < 8; ++c) {
            const float4u cv = *(const float4u*)(fplane + yx);
            float4u acc = {0.f, 0.f, 0.f, 0.f};
#pragma unroll
            for (int s = 0; s < S_NUM; ++s) {
#pragma unroll
                for (int j = 0; j < 4; ++j) {
                    int t = yx + j + offr[s];
                    t = t < 0 ? 0 : t;
                    t = t > (HW - 1) ? (HW - 1) : t;
                    acc[j] = fmaf(wv[s][j], fplane[t], acc[j]);
                }
            }
            *(float4u*)o0 = acc;
            *(float4u*)o1 = cv;
            fplane += HW;
            o0 += HW;
            o1 += HW;
        }
    }
}

extern "C" void kernel_launch(void* const* d_in, const int* in_sizes, int n_in,
                              void* d_out, int out_size, void* d_ws, size_t ws_size,
                              hipStream_t stream) {
    const float* depth      = (const float*)d_in[0];
    const float* features   = (const float*)d_in[1];
    const float* guide      = (const float*)d_in[2];
    const int*   sample_idx = (const int*)d_in[3];

    float* out = (float*)d_out;

    const int total = B_DIM * H_DIM * W_DIM;
    const int block = 256;
    dim3 grid(total / block, 1, 1);   // 1024 blocks; each does all 32 channels
    adaptive_sample_kernel<<<grid, block, 0, stream>>>(depth, features, guide,
                                                       sample_idx, out);
}

// Round 6
// 155.856 us; speedup vs baseline: 1.7295x; 1.7295x over previous
//
#include <hip/hip_runtime.h>
#include <math.h>

#define K_SIZE 5
#define PAD 2
#define DEPTH_MAX 192.0f
#define S_NUM 15
#define G_NUM (K_SIZE * K_SIZE)   // 25

// Fixed problem shape (from reference setup_inputs):
#define B_DIM 2
#define C_DIM 32
#define H_DIM 256
#define W_DIM 512
#define HW (H_DIM * W_DIM)
#define NPX (B_DIM * HW)              // 262144 pixels
#define CSPLIT 4                      // channel groups in gather kernel
#define C_PER (C_DIM / CSPLIT)        // 8 channels per thread

// ======================= Kernel A: softmax weights =======================
// One thread per pixel; writes masked softmax weights to ws in [s][pixel]
// layout (coalesced stores, coalesced reads in kernel B).
__global__ __launch_bounds__(256) void weights_kernel(
    const float* __restrict__ depth,      // [B,1,H,W]
    const float* __restrict__ guide,      // [B,H,W,25]
    const int*   __restrict__ sample_idx, // [15]
    float*       __restrict__ w)          // [S_NUM][NPX]
{
    // wave-private guide staging: 4 waves x 64 px x 25 floats = 25.6 KB
    __shared__ float gsh[4 * 64 * G_NUM];

    const int tid  = threadIdx.x;
    const int lane = tid & 63;
    const int wid  = tid >> 6;
    const int p    = blockIdx.x * 256 + tid;
    const int x = p % W_DIM;
    const int y = (p / W_DIM) % H_DIM;
    const int b = p / HW;

    int sidx[S_NUM];
#pragma unroll
    for (int s = 0; s < S_NUM; ++s) sidx[s] = sample_idx[s];

    // coalesced guide staging into wave-private LDS (no barrier needed)
    {
        const int pw = blockIdx.x * 256 + (wid << 6);
        const float* gsrc = guide + (size_t)pw * G_NUM;  // 1600 contiguous floats
        float* gw = &gsh[wid * 64 * G_NUM];
#pragma unroll
        for (int k = 0; k < G_NUM; ++k)
            gw[lane + 64 * k] = gsrc[lane + 64 * k];     // fully coalesced
    }
    const float* grow = &gsh[wid * 64 * G_NUM + lane * G_NUM]; // stride 25: conflict-free

    // gaussian positional weights, normalized
    float posw[S_NUM];
    float psum = 0.f;
#pragma unroll
    for (int s = 0; s < S_NUM; ++s) {
        const float px = (float)(sidx[s] % K_SIZE);
        const float py = (float)(sidx[s] / K_SIZE);
        const float ddx = px - (float)(K_SIZE / 2);
        const float ddy = py - (float)(K_SIZE / 2);
        posw[s] = expf(-0.5f * sqrtf(ddx * ddx + ddy * ddy));
        psum += posw[s];
    }
    const float inv_psum = 1.f / psum;

    // raw weights: valid(depth@tap) * pos_w * guide(center, idx)
    float raw[S_NUM];
    float inb_f[S_NUM];
    const int dbase = b * HW;
#pragma unroll
    for (int s = 0; s < S_NUM; ++s) {
        const int dy = sidx[s] / K_SIZE - PAD;
        const int dx = sidx[s] % K_SIZE - PAD;
        const int yy = y + dy;
        const int xx = x + dx;
        const bool inb = (yy >= 0) & (yy < H_DIM) & (xx >= 0) & (xx < W_DIM);
        float v = 0.f;
        if (inb) {
            const float d = depth[dbase + yy * W_DIM + xx];  // coalesced
            v = (d > 0.f && d < DEPTH_MAX) ? 1.f : 0.f;
        }
        raw[s]   = v * (posw[s] * inv_psum) * grow[sidx[s]];
        inb_f[s] = inb ? 1.f : 0.f;
    }

    // softmax over the 15 samples (matches jax.nn.softmax exactly)
    float mx = raw[0];
#pragma unroll
    for (int s = 1; s < S_NUM; ++s) mx = fmaxf(mx, raw[s]);
    float esum = 0.f;
    float wgt[S_NUM];
#pragma unroll
    for (int s = 0; s < S_NUM; ++s) {
        wgt[s] = expf(raw[s] - mx);
        esum += wgt[s];
    }
    const float inv_esum = 1.f / esum;

    // masked weights out (OOB taps -> 0); [s][p] layout, coalesced
#pragma unroll
    for (int s = 0; s < S_NUM; ++s)
        w[s * NPX + p] = wgt[s] * inv_esum * inb_f[s];
}

// ========================= Kernel B: gather =============================
// R2's proven scalar-tap loop: thread = pixel (lane-consecutive, coalesced),
// C_PER channels; weights read coalesced from ws. No LDS, no barriers.
__global__ __launch_bounds__(256) void gather_kernel(
    const float* __restrict__ features,   // [B,C,H,W]
    const int*   __restrict__ sample_idx, // [15]
    const float* __restrict__ w,          // [S_NUM][NPX]
    float*       __restrict__ out)        // [B,C,H,W] ++ [B,C,H,W] copy
{
    const int p = blockIdx.x * 256 + threadIdx.x;
    const int x = p % W_DIM;
    const int y = (p / W_DIM) % H_DIM;
    const int b = p / HW;
    const int c0 = blockIdx.y * C_PER;

    int sidx[S_NUM];
#pragma unroll
    for (int s = 0; s < S_NUM; ++s) sidx[s] = sample_idx[s];

    // per-pixel weights: 15 coalesced dword loads (hot in L2/L3 on re-read)
    float wgt[S_NUM];
#pragma unroll
    for (int s = 0; s < S_NUM; ++s) wgt[s] = w[s * NPX + p];

    // tap offsets, zeroed when OOB (weight is already 0 there)
    int off[S_NUM];
#pragma unroll
    for (int s = 0; s < S_NUM; ++s) {
        const int dy = sidx[s] / K_SIZE - PAD;
        const int dx = sidx[s] % K_SIZE - PAD;
        const int yy = y + dy;
        const int xx = x + dx;
        const bool inb = (yy >= 0) & (yy < H_DIM) & (xx >= 0) & (xx < W_DIM);
        off[s] = inb ? (dy * W_DIM + dx) : 0;
    }

    const size_t hw   = (size_t)HW;
    const size_t feat = (size_t)B_DIM * C_DIM * hw;
    const size_t base = ((size_t)b * C_DIM + c0) * hw + (size_t)y * W_DIM + x;
    const float* fbase = features + base;
    float*       obase = out + base;          // output 0: weighted sum
    float*       cbase = out + feat + base;   // output 1: features copy
#pragma unroll 4
    for (int c = 0; c < C_PER; ++c) {
        const float ctr = fbase[0];           // center tap (cache-hot)
        float acc = 0.f;
#pragma unroll
        for (int s = 0; s < S_NUM; ++s) {
            acc = fmaf(fbase[off[s]], wgt[s], acc);
        }
        *obase = acc;
        *cbase = ctr;
        fbase += hw;
        obase += hw;
        cbase += hw;
    }
}

// ============== Fallback: single fused kernel (R2, 82.5 us) ==============
__global__ __launch_bounds__(256) void adaptive_sample_fused(
    const float* __restrict__ depth,
    const float* __restrict__ features,
    const float* __restrict__ guide,
    const int*   __restrict__ sample_idx,
    float*       __restrict__ out)
{
    __shared__ float gsh[4][64 * G_NUM];

    const int lane = threadIdx.x & 63;
    const int wid  = threadIdx.x >> 6;
    const int p = blockIdx.x * 256 + threadIdx.x;
    const int x = p % W_DIM;
    const int y = (p / W_DIM) % H_DIM;
    const int b = p / HW;
    const int c0 = blockIdx.y * C_PER;

    int sidx[S_NUM];
#pragma unroll
    for (int s = 0; s < S_NUM; ++s) sidx[s] = sample_idx[s];

    {
        const int pw = blockIdx.x * 256 + (wid << 6);
        const float* gsrc = guide + (size_t)pw * G_NUM;
        float* gw = gsh[wid];
#pragma unroll
        for (int k = 0; k < G_NUM; ++k)
            gw[lane + 64 * k] = gsrc[lane + 64 * k];
    }
    const float* grow = &gsh[wid][lane * G_NUM];

    float posw[S_NUM];
    float psum = 0.f;
#pragma unroll
    for (int s = 0; s < S_NUM; ++s) {
        const float px = (float)(sidx[s] % K_SIZE);
        const float py = (float)(sidx[s] / K_SIZE);
        const float ddx = px - (float)(K_SIZE / 2);
        const float ddy = py - (float)(K_SIZE / 2);
        posw[s] = expf(-0.5f * sqrtf(ddx * ddx + ddy * ddy));
        psum += posw[s];
    }
    const float inv_psum = 1.f / psum;

    float raw[S_NUM];
    int   off[S_NUM];
    float inb_f[S_NUM];
    const int dbase = b * HW;
#pragma unroll
    for (int s = 0; s < S_NUM; ++s) {
        const int dy = sidx[s] / K_SIZE - PAD;
        const int dx = sidx[s] % K_SIZE - PAD;
        const int yy = y + dy;
        const int xx = x + dx;
        const bool inb = (yy >= 0) & (yy < H_DIM) & (xx >= 0) & (xx < W_DIM);
        float v = 0.f;
        if (inb) {
            const float d = depth[dbase + yy * W_DIM + xx];
            v = (d > 0.f && d < DEPTH_MAX) ? 1.f : 0.f;
        }
        raw[s]   = v * (posw[s] * inv_psum) * grow[sidx[s]];
        off[s]   = inb ? (dy * W_DIM + dx) : 0;
        inb_f[s] = inb ? 1.f : 0.f;
    }

    float mx = raw[0];
#pragma unroll
    for (int s = 1; s < S_NUM; ++s) mx = fmaxf(mx, raw[s]);
    float esum = 0.f;
    float wgt[S_NUM];
#pragma unroll
    for (int s = 0; s < S_NUM; ++s) {
        wgt[s] = expf(raw[s] - mx);
        esum += wgt[s];
    }
    const float inv_esum = 1.f / esum;
#pragma unroll
    for (int s = 0; s < S_NUM; ++s)
        wgt[s] = wgt[s] * inv_esum * inb_f[s];

    const size_t hw   = (size_t)HW;
    const size_t feat = (size_t)B_DIM * C_DIM * hw;
    const size_t base = ((size_t)b * C_DIM + c0) * hw + (size_t)y * W_DIM + x;
    const float* fbase = features + base;
    float*       obase = out + base;
    float*       cbase = out + feat + base;
#pragma unroll 4
    for (int c = 0; c < C_PER; ++c) {
        const float ctr = fbase[0];
        float acc = 0.f;
#pragma unroll
        for (int s = 0; s < S_NUM; ++s) {
            acc = fmaf(fbase[off[s]], wgt[s], acc);
        }
        *obase = acc;
        *cbase = ctr;
        fbase += hw;
        obase += hw;
        cbase += hw;
    }
}

extern "C" void kernel_launch(void* const* d_in, const int* in_sizes, int n_in,
                              void* d_out, int out_size, void* d_ws, size_t ws_size,
                              hipStream_t stream) {
    const float* depth      = (const float*)d_in[0];
    const float* features   = (const float*)d_in[1];
    const float* guide      = (const float*)d_in[2];
    const int*   sample_idx = (const int*)d_in[3];

    float* out = (float*)d_out;
    const size_t ws_needed = (size_t)S_NUM * NPX * sizeof(float);  // 15.7 MB

    const int blocks = NPX / 256;  // 1024

    if (ws_size >= ws_needed && d_ws != nullptr) {
        float* w = (float*)d_ws;
        weights_kernel<<<blocks, 256, 0, stream>>>(depth, guide, sample_idx, w);
        dim3 grid(blocks, CSPLIT, 1);
        gather_kernel<<<grid, 256, 0, stream>>>(features, sample_idx, w, out);
    } else {
        // ws too small: known-good fused path
        dim3 grid(blocks, CSPLIT, 1);
        adaptive_sample_fused<<<grid, 256, 0, stream>>>(depth, features, guide,
                                                        sample_idx, out);
    }
}